// Round 3
// baseline (375.211 us; speedup 1.0000x reference)
//
#include <hip/hip_runtime.h>
#include <math.h>

// Problem constants (from reference setup_inputs)
constexpr int B = 4;
constexpr int N = 512;     // rois per batch
constexpr int C = 256;     // channels
constexpr int H = 256;
constexpr int W = 256;
constexpr int NPT = 5;     // center, front, back, left, right
constexpr int PTS = N * NPT;   // 2560 points per batch

constexpr int RT  = 8;         // rows per y-tile
constexpr int NT  = H / RT;    // 32 tiles
constexpr int CG  = 4;         // channels per gather block
constexpr int NCG = C / CG;    // 64 channel groups
constexpr int CAP = PTS;       // worst-case list capacity per (b,tile)

// ws layout: [0,512): u32 counts[B*NT]; [512, ...): 16B records[B*NT*CAP]
// record = { u32 (n<<3|p), f32 xs, f32 ys, u32 pad }
constexpr size_t REC_OFF = 512;

__device__ __forceinline__ void point_xy(const float* __restrict__ rois,
                                         int b, int n, int p,
                                         float& xs, float& ys) {
    const float* roi = rois + ((size_t)b * N + n) * 7;
    const float cx = roi[0], cy = roi[1];
    const float hx = 0.5f * roi[3];
    const float hy = 0.5f * roi[4];
    float si, co;
    sincosf(roi[6], &si, &co);
    float px = cx, py = cy;
    if      (p == 1) { px = cx - hx * co; py = cy + hx * si; }  // front
    else if (p == 2) { px = cx + hx * co; py = cy - hx * si; }  // back
    else if (p == 3) { px = cx - hy * si; py = cy - hy * co; }  // left
    else if (p == 4) { px = cx + hy * si; py = cy + hy * co; }  // right
    xs = (px + 51.2f) * 2.5f;
    ys = (py + 51.2f) * 2.5f;
}

__global__ __launch_bounds__(128)
void k0_zero(unsigned* __restrict__ cnt) {
    cnt[threadIdx.x] = 0u;   // B*NT = 128 counters
}

__global__ __launch_bounds__(256)
void k1_bucket(const float* __restrict__ rois, unsigned char* __restrict__ ws) {
    const int gid = blockIdx.x * 256 + threadIdx.x;
    if (gid >= B * PTS) return;
    const int b  = gid / PTS;
    const int qq = gid - b * PTS;
    const int n  = qq / NPT;
    const int p  = qq - n * NPT;

    float xs, ys;
    point_xy(rois, b, n, p, xs, ys);

    const int yi = (int)floorf(ys);
    const int y0 = min(max(yi, 0), H - 1);
    const int tile = y0 >> 3;   // RT = 8

    unsigned* cnt = (unsigned*)ws;
    const unsigned slot = atomicAdd(&cnt[b * NT + tile], 1u);
    float4* rec = (float4*)(ws + REC_OFF);
    float4 r;
    r.x = __uint_as_float((unsigned)((n << 3) | p));
    r.y = xs;
    r.z = ys;
    r.w = 0.0f;
    rec[((size_t)(b * NT + tile)) * CAP + slot] = r;
}

// LDS slab per channel: 9 rows x 256 cols, padded +8 floats so the 4 channel
// slabs start 8 banks apart (2312 mod 32 == 8) -> conflict-free ch fan-out.
constexpr int SLAB = (RT + 1) * W + 8;   // 2312 floats

__global__ __launch_bounds__(256)
void k2_gather(const float* __restrict__ feats,
               const unsigned char* __restrict__ ws,
               float* __restrict__ out) {
    const int t  = blockIdx.x;   // y-tile  [0,32)
    const int cg = blockIdx.y;   // channel group [0,64)
    const int b  = blockIdx.z;   // batch [0,4)
    const int tid = threadIdx.x;

    __shared__ float lds[CG * SLAB];

    // ---- Stage: coalesced float4 streaming of 4 planes x 9 rows ----
    // total float4 = CG * 9 rows * 64 = 2304
    for (int i = tid; i < CG * (RT + 1) * (W / 4); i += 256) {
        const int ch  = i / ((RT + 1) * (W / 4));
        const int rem = i - ch * ((RT + 1) * (W / 4));
        const int r   = rem / (W / 4);
        const int c4  = rem - r * (W / 4);
        const int grow = min(t * RT + r, H - 1);
        const float4 v = *(const float4*)&feats[(((size_t)b * C + cg * CG + ch) * H + grow) * W + c4 * 4];
        *(float4*)&lds[ch * SLAB + r * W + c4 * 4] = v;
    }

    const unsigned m = ((const unsigned*)ws)[b * NT + t];
    const float4* rec = (const float4*)(ws + REC_OFF) + (size_t)(b * NT + t) * CAP;

    __syncthreads();

    // ---- Process: 4 threads per point (one per channel), 64 point slots ----
    const int ch = tid & 3;
    const int pi = tid >> 2;
    const float* slab = lds + ch * SLAB;

    for (unsigned i = pi; i < m; i += 64) {
        const float4 r4 = rec[i];
        const unsigned np = __float_as_uint(r4.x);
        const int n = np >> 3;
        const int p = np & 7;
        const float xs = r4.y;
        const float ys = r4.z;

        const int xi = (int)floorf(xs);
        const int yi = (int)floorf(ys);
        const int x0 = min(max(xi, 0), W - 1);
        const int x1 = min(max(xi + 1, 0), W - 1);
        const int y0 = min(max(yi, 0), H - 1);
        const int y1 = min(max(yi + 1, 0), H - 1);

        const float x0f = (float)x0, x1f = (float)x1;
        const float y0f = (float)y0, y1f = (float)y1;
        const float wa = (x1f - xs) * (y1f - ys);
        const float wb = (x1f - xs) * (ys - y0f);
        const float wc = (xs - x0f) * (y1f - ys);
        const float wd = (xs - x0f) * (ys - y0f);

        const int ly0 = y0 - t * RT;   // in [0, RT)
        const int ly1 = y1 - t * RT;   // in [0, RT]  (overlap row loaded)

        const float Ia = slab[ly0 * W + x0];
        const float Ib = slab[ly1 * W + x0];
        const float Ic = slab[ly0 * W + x1];
        const float Id = slab[ly1 * W + x1];

        out[(((size_t)b * N + n) * NPT + p) * C + cg * CG + ch] =
            Ia * wa + Ib * wb + Ic * wc + Id * wd;
    }
}

extern "C" void kernel_launch(void* const* d_in, const int* in_sizes, int n_in,
                              void* d_out, int out_size, void* d_ws, size_t ws_size,
                              hipStream_t stream) {
    const float* feats = (const float*)d_in[0];  // (B,C,H,W) f32
    const float* rois  = (const float*)d_in[1];  // (B,N,7)   f32
    float* out = (float*)d_out;                  // (B,N,NPT*C) f32
    unsigned char* ws = (unsigned char*)d_ws;

    k0_zero<<<1, 128, 0, stream>>>((unsigned*)ws);
    k1_bucket<<<(B * PTS + 255) / 256, 256, 0, stream>>>(rois, ws);
    k2_gather<<<dim3(NT, NCG, B), 256, 0, stream>>>(feats, ws, out);
}